// Round 8
// baseline (341.274 us; speedup 1.0000x reference)
//
#include <hip/hip_runtime.h>
#include <hip/hip_bf16.h>
#include <stdint.h>

// ---------------- common types / helpers ----------------
typedef __attribute__((ext_vector_type(8))) short  bf16x8;   // 8 bf16 in 4 VGPRs
typedef __attribute__((ext_vector_type(4))) float  f32x4;
typedef __attribute__((ext_vector_type(4))) unsigned int u32x4;
typedef __attribute__((ext_vector_type(2))) unsigned int u32x2;

#define LOG2E 1.4426950408889634f

__device__ __forceinline__ unsigned short f2bf(float f) {
  unsigned int u = __builtin_bit_cast(unsigned int, f);
  u += 0x7fffu + ((u >> 16) & 1u);          // round-to-nearest-even
  return (unsigned short)(u >> 16);
}

// packed 2xfp32 -> 2xbf16 (v_cvt_pk_bf16_f32 on gfx950), returned as u32
__device__ __forceinline__ unsigned int pk2(float a, float b) {
  __hip_bfloat162 h = __float22bfloat162_rn(make_float2(a, b));
  unsigned int u;
  __builtin_memcpy(&u, &h, 4);
  return u;
}

// async global->LDS, 16B per lane. LDS dest = wave-uniform base + lane*16.
__device__ __forceinline__ void async16(const void* g, void* l) {
  __builtin_amdgcn_global_load_lds(
      (const __attribute__((address_space(1))) unsigned int*)g,
      (__attribute__((address_space(3))) unsigned int*)l,
      16, 0, 0);
}

// ---------------- cast all fp32 inputs -> bf16 in one launch ----------------
// x: 2,097,152 float4; weights: 4 x 262,144 float4. Grid 12288 x 256.
__global__ __launch_bounds__(256) void cast_all(
    const float* __restrict__ x,
    const float* __restrict__ Wq, const float* __restrict__ Wk,
    const float* __restrict__ Wv, const float* __restrict__ Wo,
    unsigned short* __restrict__ xb, unsigned short* __restrict__ wqkv,
    unsigned short* __restrict__ wo) {
  int i = blockIdx.x * 256 + threadIdx.x;
  const float* src;
  unsigned short* dst;
  int off;
  if (i < 2097152) {
    src = x; dst = xb; off = i;
  } else {
    int j = i - 2097152;
    int seg = j >> 18; off = j & 262143;
    src = (seg == 0) ? Wq : (seg == 1) ? Wk : (seg == 2) ? Wv : Wo;
    dst = (seg < 3) ? (wqkv + (size_t)seg * 1048576) : wo;
  }
  float4 f = ((const float4*)src)[off];
  uint2 o;
  o.x = pk2(f.x, f.y);
  o.y = pk2(f.z, f.w);
  ((uint2*)dst)[off] = o;
}

// ---------------- QKV GEMM: C[8192,3072] = x_bf16 @ Wqkv^T + bias ----------------
// r7 structure (128x128, dbuf, counted vmcnt, 32 KB LDS with epi overlay) +
// r8 address hoisting: all LDS read/staging addresses are lane-constant bases
// + literal offsets (t unrolled by 2 so `cur` is compile-time).
__global__ __launch_bounds__(256) void gemm_qkv(
    const unsigned short* __restrict__ xb, const unsigned short* __restrict__ wqkv,
    const float* __restrict__ bq, const float* __restrict__ bk, const float* __restrict__ bv,
    unsigned short* __restrict__ qb, unsigned short* __restrict__ kb,
    unsigned short* __restrict__ vb) {
  // elems: [0..4095]=A buf0, [4096..8191]=A buf1, [8192..12287]=B buf0,
  // [12288..16383]=B buf1; epilogue: wave wv reuses sh + wv*4096 (64x64).
  __shared__ __align__(16) unsigned short sh[16384];          // 32 KB
  const int bid = blockIdx.x;
  const int xcd = bid & 7, idx = bid >> 3;
  const int nt = xcd * 3 + (idx % 3);            // 24 n-tiles: 3 per XCD
  const int mt = idx / 3;                        // 64 m-tiles
  const int m0 = mt * 128, n0 = nt * 128;
  const int tid = threadIdx.x;
  const int wv = tid >> 6, lane = tid & 63, qq = lane >> 4, ln = lane & 15;
  const int wm = wv & 1, wn = wv >> 1;
  const int K = 1024;

  f32x4 acc[4][4];
#pragma unroll
  for (int i = 0; i < 4; ++i)
#pragma unroll
    for (int j = 0; j < 4; ++j) acc[i][j] = f32x4{0.f, 0.f, 0.f, 0.f};

  // ---- hoisted lane-constant addresses ----
  // LDS read bases: row = {wm|wn}*64 + i*16 + ln; (row>>1)&3 == (ln>>1)&3.
  const int xsl = (qq ^ ((ln >> 1) & 3)) << 3;             // elem offset
  const unsigned short* baseA = sh + (wm * 64 + ln) * 32 + xsl;
  const unsigned short* baseB = sh + 8192 + (wn * 64 + ln) * 32 + xsl;
  // staging: jp = (wv*2+i)*64+lane; i=1 differs by +16 rows (same c).
  int jp = wv * 128 + lane;
  int srow = jp >> 2, scp = jp & 3;
  int sc = scp ^ ((srow >> 1) & 3);
  const unsigned short* xgl = xb   + (size_t)(m0 + srow) * K + sc * 8;
  const unsigned short* wgl = wqkv + (size_t)(n0 + srow) * K + sc * 8;
  const unsigned short* xgl2 = xgl + (size_t)16 * K;       // +16 rows
  const unsigned short* wgl2 = wgl + (size_t)16 * K;
  unsigned short* ldsA0 = sh + (wv * 2) * 512;             // chunk dests
  unsigned short* ldsB0 = sh + 8192 + (wv * 2) * 512;

  auto stage = [&](int buf) {                    // 4 loads/thread, then advance
    async16(xgl,  ldsA0 + buf * 4096);
    async16(xgl2, ldsA0 + buf * 4096 + 512);
    async16(wgl,  ldsB0 + buf * 4096);
    async16(wgl2, ldsB0 + buf * 4096 + 512);
    xgl += 32; xgl2 += 32; wgl += 32; wgl2 += 32;          // next k-step
  };

  stage(0);                                      // tile 0 -> buf0
  auto step = [&](int t, int cur) {              // cur is a call-site literal
    if (t < 31) {
      stage(cur ^ 1);
      asm volatile("s_waitcnt vmcnt(4)" ::: "memory");     // retire stage(t)
    } else {
      asm volatile("s_waitcnt vmcnt(0)" ::: "memory");
    }
    __builtin_amdgcn_s_barrier();
    bf16x8 af[4], bf[4];
#pragma unroll
    for (int i = 0; i < 4; ++i) af[i] = *(const bf16x8*)(baseA + cur * 4096 + i * 512);
#pragma unroll
    for (int j = 0; j < 4; ++j) bf[j] = *(const bf16x8*)(baseB + cur * 4096 + j * 512);
#pragma unroll
    for (int i = 0; i < 4; ++i)
#pragma unroll
      for (int j = 0; j < 4; ++j)
        acc[i][j] = __builtin_amdgcn_mfma_f32_16x16x32_bf16(af[i], bf[j], acc[i][j], 0, 0, 0);
    __builtin_amdgcn_s_barrier();
  };
  for (int t = 0; t < 32; t += 2) { step(t, 0); step(t + 1, 1); }
  // after final barrier: all waves done with tile LDS -> safe to overlay epi

  const int nblk = n0 >> 10;                           // 0=Q 1=K 2=V
  const float* bias = (nblk == 0) ? bq : (nblk == 1) ? bk : bv;
  const float scale = (nblk == 0) ? (0.125f * LOG2E) : 1.0f;
  unsigned short* ep = sh + wv * 4096;                 // 64x64, swizzled
  const int ncol0 = (n0 & 1023) + wn * 64;
  const int head  = ncol0 >> 6;
  const int mbase = m0 + wm * 64;
  const int b     = mbase >> 11, sbase = mbase & 2047;
  unsigned short* dst = (nblk == 0) ? qb : (nblk == 1) ? kb : vb;

  if (nblk != 2) {
    // ---- Q/K: LDS layout [m(s)][n(d)], stride 64, XOR-swizzled chunks ----
#pragma unroll
    for (int j = 0; j < 4; ++j) {
      float bs = bias[ncol0 + j * 16 + ln] * scale;
      int csl = j * 2 + (ln >> 3), c7 = ln & 7;
#pragma unroll
      for (int i = 0; i < 4; ++i)
#pragma unroll
        for (int r = 0; r < 4; ++r) {
          int row = i * 16 + qq * 4 + r;
          ep[row * 64 + ((csl ^ (row & 7)) << 3) + c7] = f2bf(acc[i][j][r] * scale + bs);
        }
    }
    unsigned short* gout = dst + (((size_t)(b * 16 + head)) * 2048 + sbase) * 64;
#pragma unroll
    for (int h = 0; h < 2; ++h)
#pragma unroll
      for (int p = 0; p < 4; ++p) {
        int rr = (lane >> 2) + p * 16;
        int c4 = lane & 3;
        ulonglong2 v = *(const ulonglong2*)(ep + rr * 64 + (((h * 4 + c4) ^ (rr & 7)) << 3));
        *(ulonglong2*)(gout + (size_t)rr * 64 + h * 32 + c4 * 8) = v;
      }
  } else {
    // ---- V: LDS layout [n(d)][m(s)], stride 64, XOR-swizzled; b64 writes ----
#pragma unroll
    for (int j = 0; j < 4; ++j) {
      float bs = bias[ncol0 + j * 16 + ln];
      int row = j * 16 + ln;
      int rs = row & 7;
#pragma unroll
      for (int i = 0; i < 4; ++i) {
        uint2 pk;
        pk.x = pk2(acc[i][j][0] + bs, acc[i][j][1] + bs);
        pk.y = pk2(acc[i][j][2] + bs, acc[i][j][3] + bs);
        int slot = (i * 2 + (qq >> 1)) ^ rs;
        *(uint2*)(ep + row * 64 + (slot << 3) + ((qq & 1) << 2)) = pk;
      }
    }
    unsigned short* gout = dst + ((size_t)(b * 16 + head)) * 64 * 2048 + sbase;
#pragma unroll
    for (int p = 0; p < 8; ++p) {
      int dr = (lane >> 3) + p * 8;
      int c8 = lane & 7;
      ulonglong2 v = *(const ulonglong2*)(ep + dr * 64 + ((c8 ^ (dr & 7)) << 3));
      *(ulonglong2*)(gout + (size_t)dr * 2048 + c8 * 8) = v;
    }
  }
}

// ---------------- flash attention: r6 structure + hoisted addressing ----------
// Identical math/sync to r6 (passed, 92.9 us). r8 change: all LDS fragment
// addresses are 4 lane-constant bases + literal offsets (kt unrolled by 2 so
// `cur` is compile-time); staging uses 4 pre-advanced global pointers.
// Theory: VALUBusy 55% was dominated by per-tile address recomputation.
__global__ __launch_bounds__(256, 2) void attn_kernel(
    const unsigned short* __restrict__ qb, const unsigned short* __restrict__ kb,
    const unsigned short* __restrict__ vb, unsigned short* __restrict__ ctx) {
  // elems: [0..4095]=K buf0, [4096..8191]=K buf1, [8192..12287]=V^T buf0,
  // [12288..16383]=V^T buf1; epilogue reuses all 32 KB.
  __shared__ __align__(16) unsigned short sh[16384];
  const int bid = blockIdx.x;
  const int xcd = bid & 7, idx = bid >> 3;       // 64 blocks per XCD
  const int bh = xcd * 8 + (idx >> 3);           // 8 heads per XCD
  const int q0 = (idx & 7) * 256;                // 8 q-tiles of 256 rows
  const int tid = threadIdx.x;
  const int wv = tid >> 6, lane = tid & 63, qq = lane >> 4, ln = lane & 15;

  bf16x8 qf[4][2];
  {
    const unsigned short* qbase = qb + ((size_t)bh * 2048 + q0 + wv * 64) * 64;
#pragma unroll
    for (int rb = 0; rb < 4; ++rb)
#pragma unroll
      for (int kq = 0; kq < 2; ++kq)
        qf[rb][kq] = *(const bf16x8*)(qbase + (rb * 16 + ln) * 64 + kq * 32 + qq * 8);
  }

  f32x4 o_acc[4][4];
  float l_i[4] = {0.f, 0.f, 0.f, 0.f};
#pragma unroll
  for (int rb = 0; rb < 4; ++rb)
#pragma unroll
    for (int nt = 0; nt < 4; ++nt) o_acc[rb][nt] = f32x4{0.f, 0.f, 0.f, 0.f};
  const f32x4 z4 = f32x4{0.f, 0.f, 0.f, 0.f};

  // ---- hoisted lane-constant LDS read bases (elem units) ----
  const int l7 = ln & 7;
  const unsigned short* baseK0 = sh + ln * 64 + ((qq ^ l7) << 3);
  const unsigned short* baseK4 = sh + ln * 64 + (((4 + qq) ^ l7) << 3);
  const unsigned short* baseV0 = baseK0 + 8192;
  const unsigned short* baseV4 = baseK4 + 8192;

  // ---- hoisted staging pointers: row/c lane-constant; +8 rows => same c ----
  const int cc0 = wv * 2;
  int jp = cc0 * 64 + lane;
  int srow = jp >> 3, sc = (jp & 7) ^ (srow & 7);          // (srow+8)&7 == srow&7
  const unsigned short* kgl  = kb + (size_t)bh * 2048 * 64 + (size_t)srow * 64 + sc * 8;
  const unsigned short* kgl2 = kgl + 512;                  // +8 rows
  const unsigned short* vgl  = vb + (size_t)bh * 64 * 2048 + (size_t)srow * 2048 + sc * 8;
  const unsigned short* vgl2 = vgl + 16384;                // +8 d-rows
  unsigned short* ldsK = sh + cc0 * 512;
  unsigned short* ldsV = sh + 8192 + cc0 * 512;

  auto stageKV = [&](int buf) {                  // 4 loads/thread, then advance
    async16(kgl,  ldsK + buf * 4096);
    async16(kgl2, ldsK + buf * 4096 + 512);
    async16(vgl,  ldsV + buf * 4096);
    async16(vgl2, ldsV + buf * 4096 + 512);
    kgl += 4096; kgl2 += 4096;                   // next K tile: +64 rows
    vgl += 64;   vgl2 += 64;                     // next V tile: +64 kpos
  };

  stageKV(0);
  asm volatile("s_waitcnt vmcnt(0)" ::: "memory");
  __builtin_amdgcn_s_barrier();

  auto tile = [&](int kt, int cur) {             // cur is a call-site literal
    if (kt < 31) stageKV(cur ^ 1);

    bf16x8 kf[4][2];
#pragma unroll
    for (int ct = 0; ct < 4; ++ct) {
      kf[ct][0] = *(const bf16x8*)(baseK0 + cur * 4096 + ct * 1024);
      kf[ct][1] = *(const bf16x8*)(baseK4 + cur * 4096 + ct * 1024);
    }
    bf16x8 vf[2][4];
#pragma unroll
    for (int nt = 0; nt < 4; ++nt) {
      vf[0][nt] = *(const bf16x8*)(baseV0 + cur * 4096 + nt * 1024);
      vf[1][nt] = *(const bf16x8*)(baseV4 + cur * 4096 + nt * 1024);
    }

    auto QK = [&](const bf16x8& q0f, const bf16x8& q1f, f32x4* s) {
#pragma unroll
      for (int ct = 0; ct < 4; ++ct) {
        s[ct] = __builtin_amdgcn_mfma_f32_16x16x32_bf16(kf[ct][0], q0f, z4, 0, 0, 0);
        s[ct] = __builtin_amdgcn_mfma_f32_16x16x32_bf16(kf[ct][1], q1f, s[ct], 0, 0, 0);
      }
    };
    auto SM = [&](float& li, const f32x4* s, bf16x8* pfo) {
      unsigned int W[4][2];
#pragma unroll
      for (int ct = 0; ct < 4; ++ct) {
        float p0 = __builtin_amdgcn_exp2f(s[ct][0]);
        float p1 = __builtin_amdgcn_exp2f(s[ct][1]);
        float p2 = __builtin_amdgcn_exp2f(s[ct][2]);
        float p3 = __builtin_amdgcn_exp2f(s[ct][3]);
        li += (p0 + p1) + (p2 + p3);             // fp32 denominator (r4 lesson)
        W[ct][0] = pk2(p0, p1);
        W[ct][1] = pk2(p2, p3);
      }
#pragma unroll
      for (int kk = 0; kk < 2; ++kk) {
        u32x2 a1 = __builtin_amdgcn_permlane32_swap(W[2 * kk][0], W[2 * kk + 1][0], false, false);
        u32x2 a2 = __builtin_amdgcn_permlane16_swap(a1.x, a1.y, false, false);
        u32x2 b1 = __builtin_amdgcn_permlane32_swap(W[2 * kk][1], W[2 * kk + 1][1], false, false);
        u32x2 b2 = __builtin_amdgcn_permlane16_swap(b1.x, b1.y, false, false);
        u32x4 pw = {a2.x, b2.x, a2.y, b2.y};
        pfo[kk] = __builtin_bit_cast(bf16x8, pw);
      }
    };
    auto PV = [&](f32x4* oa, const bf16x8* pfi) {
#pragma unroll
      for (int kk = 0; kk < 2; ++kk)
#pragma unroll
        for (int nt = 0; nt < 4; ++nt)
          oa[nt] = __builtin_amdgcn_mfma_f32_16x16x32_bf16(vf[kk][nt], pfi[kk], oa[nt], 0, 0, 0);
    };

    f32x4 s0[4], s1[4], s2[4], s3[4];
    bf16x8 p0[2], p1[2], p2[2], p3[2];
    QK(qf[0][0], qf[0][1], s0);
    QK(qf[1][0], qf[1][1], s1);  SM(l_i[0], s0, p0);
    QK(qf[2][0], qf[2][1], s2);  SM(l_i[1], s1, p1);  PV(o_acc[0], p0);
    QK(qf[3][0], qf[3][1], s3);  SM(l_i[2], s2, p2);  PV(o_acc[1], p1);
                                 SM(l_i[3], s3, p3);  PV(o_acc[2], p2);
                                                      PV(o_acc[3], p3);

    if (kt < 31) asm volatile("s_waitcnt vmcnt(0)" ::: "memory");
    __builtin_amdgcn_s_barrier();
  };
  for (int kt = 0; kt < 32; kt += 2) { tile(kt, 0); tile(kt + 1, 1); }

  // finalize row sums (cross-quad), normalize, transpose via reused sh (32 KB)
  unsigned short* ep = sh;                       // 256 rows x 64 cols, swizzled
#pragma unroll
  for (int rb = 0; rb < 4; ++rb) {
    l_i[rb] += __shfl_xor(l_i[rb], 16);
    l_i[rb] += __shfl_xor(l_i[rb], 32);
    float inv = 1.0f / l_i[rb];
    int row = wv * 64 + rb * 16 + ln;
    int rs = row & 7;
#pragma unroll
    for (int nt = 0; nt < 4; ++nt) {
      uint2 pk;
      pk.x = pk2(o_acc[rb][nt][0] * inv, o_acc[rb][nt][1] * inv);
      pk.y = pk2(o_acc[rb][nt][2] * inv, o_acc[rb][nt][3] * inv);
      *(uint2*)(ep + row * 64 + (((nt * 2 + (qq >> 1)) ^ rs) << 3) + ((qq & 1) << 2)) = pk;
    }
  }
  // same-wave transposed read: thread tid reads row tid; no barrier needed.
  {
    const int b = bh >> 4, h = bh & 15;
    int r = tid;
    int rs2 = r & 7;
    size_t gbase = ((size_t)(b * 2048 + q0 + r)) * 1024 + h * 64;
    const unsigned short* lsrc = ep + r * 64;
#pragma unroll
    for (int j = 0; j < 8; ++j)
      *(ulonglong2*)(ctx + gbase + (size_t)j * 8) =
          *(const ulonglong2*)(lsrc + ((j ^ rs2) << 3));
  }
}

// ---------------- output GEMM: out[8192,1024] = ctx @ Wo^T + bo (fp32 out) ----------------
// r7 version unchanged (64x128 tiles, grid 1024, 4 blocks/CU, counted vmcnt).
__global__ __launch_bounds__(256, 4) void gemm_out(
    const unsigned short* __restrict__ ctx, const unsigned short* __restrict__ wo,
    const float* __restrict__ bo, float* __restrict__ out) {
  __shared__ __align__(16) unsigned short Asd[2][64 * 32];    // 8 KB
  __shared__ __align__(16) unsigned short Bsd[2][128 * 32];   // 16 KB
  const int bid = blockIdx.x;
  const int n0 = (bid & 7) * 128;
  const int m0 = (bid >> 3) * 64;
  const int tid = threadIdx.x;
  const int wv = tid >> 6, lane = tid & 63, qq = lane >> 4, ln = lane & 15;
  const int K = 1024;

  f32x4 acc[4][2];
#pragma unroll
  for (int i = 0; i < 4; ++i)
#pragma unroll
    for (int j = 0; j < 2; ++j) acc[i][j] = f32x4{0.f, 0.f, 0.f, 0.f};

  auto stage = [&](int t, int buf) {             // 3 loads per thread
    {
      int jp = wv * 64 + lane;
      int row = jp >> 2, cp = jp & 3;
      int c = cp ^ ((row >> 1) & 3);
      async16(ctx + (size_t)(m0 + row) * K + t * 32 + c * 8, Asd[buf] + wv * 512);
    }
#pragma unroll
    for (int i = 0; i < 2; ++i) {
      int cc = wv * 2 + i;
      int jp = cc * 64 + lane;
      int row = jp >> 2, cp = jp & 3;
      int c = cp ^ ((row >> 1) & 3);
      async16(wo + (size_t)(n0 + row) * K + t * 32 + c * 8, Bsd[buf] + cc * 512);
    }
  };

  stage(0, 0);
  for (int t = 0; t < 32; ++t) {
    const int cur = t & 1;
    if (t < 31) {
      stage(t + 1, cur ^ 1);
      asm volatile("s_waitcnt vmcnt(3)" ::: "memory");
    } else {
      asm volatile("s_waitcnt vmcnt(0)" ::: "memory");
    }
    __builtin_amdgcn_s_barrier();

    bf16x8 af[4], bf[2];
#pragma unroll
    for (int i = 0; i < 4; ++i) {
      int row = i * 16 + ln;
      af[i] = *(const bf16x8*)(Asd[cur] + row * 32 + (qq ^ ((row >> 1) & 3)) * 8);
    }
#pragma unroll
    for (int j = 0; j < 2; ++j) {
      int row = wv * 32 + j * 16 + ln;
      bf[j] = *(const bf16x8*)(Bsd[cur] + row * 32 + (qq ^ ((row >> 1) & 3)) * 8);
    }
#pragma unroll
    for (int i = 0; i < 4; ++i)
#pragma unroll
      for (int j = 0; j < 2; ++j)
        acc[i][j] = __builtin_amdgcn_mfma_f32_16x16x32_bf16(af[i], bf[j], acc[i][j], 0, 0, 0);
    __builtin_amdgcn_s_barrier();
  }

#pragma unroll
  for (int j = 0; j < 2; ++j) {
    int n = n0 + wv * 32 + j * 16 + ln;
    float bsv = bo[n];
#pragma unroll
    for (int i = 0; i < 4; ++i) {
#pragma unroll
      for (int r = 0; r < 4; ++r) {
        int m = m0 + i * 16 + qq * 4 + r;
        out[(size_t)m * 1024 + n] = acc[i][j][r] + bsv;
      }
    }
  }
}

// ---------------- launch ----------------
extern "C" void kernel_launch(void* const* d_in, const int* in_sizes, int n_in,
                              void* d_out, int out_size, void* d_ws, size_t ws_size,
                              hipStream_t stream) {
  const float* x  = (const float*)d_in[0];
  const float* Wq = (const float*)d_in[1];
  const float* bq = (const float*)d_in[2];
  const float* Wk = (const float*)d_in[3];
  const float* bk = (const float*)d_in[4];
  const float* Wv = (const float*)d_in[5];
  const float* bv = (const float*)d_in[6];
  const float* Wo = (const float*)d_in[7];
  const float* bo = (const float*)d_in[8];
  float* out = (float*)d_out;

  char* ws = (char*)d_ws;
  unsigned short* xb   = (unsigned short*)(ws);                      // 16M
  unsigned short* ctxb = (unsigned short*)(ws);                      // reuse
  unsigned short* qb   = (unsigned short*)(ws + ((size_t)16 << 20)); // 16M
  unsigned short* kbuf = (unsigned short*)(ws + ((size_t)32 << 20)); // 16M
  unsigned short* vbuf = (unsigned short*)(ws + ((size_t)48 << 20)); // 16M
  unsigned short* wqkv = (unsigned short*)(ws + ((size_t)64 << 20)); // 6M
  unsigned short* wo   = (unsigned short*)(ws + ((size_t)70 << 20)); // 2M

  cast_all<<<12288, 256, 0, stream>>>(x, Wq, Wk, Wv, Wo, xb, wqkv, wo);

  gemm_qkv<<<1536, 256, 0, stream>>>(xb, wqkv, bq, bk, bv, qb, kbuf, vbuf);
  attn_kernel<<<512, 256, 0, stream>>>(qb, kbuf, vbuf, ctxb);
  gemm_out<<<1024, 256, 0, stream>>>(ctxb, wo, bo, out);
}